// Round 1
// baseline (660.550 us; speedup 1.0000x reference)
//
#include <hip/hip_runtime.h>
#include <hip/hip_bf16.h>

// TernaryConv2d: x[16,64,224,224] f32, w[64,64,3,3] f32 -> ternarize (per-co
// {-1,0,+1}*alpha) -> conv3x3 pad1 + bias -> out[16,64,224,224] f32.
//
// Strategy: bf16 MFMA implicit GEMM. Ternary pattern kept as exact {-1,0,+1}
// bf16 (A operand); alpha applied in fp32 epilogue -> only error source is
// x->bf16 rounding. Block tile: M=64 (all C_out) x N=256 spatial (8 rows x 32
// cols). 8 waves, each wave M=64 x N=32. K = 9(kh,kw) x 64ci = 576, stepped 32.

typedef short short8 __attribute__((ext_vector_type(8)));
typedef short short4v __attribute__((ext_vector_type(4)));
typedef float f32x4 __attribute__((ext_vector_type(4)));
typedef __bf16 bf16x8 __attribute__((ext_vector_type(8)));

#define HH 224
#define WW 224
#define CIN 64
#define COUT 64
#define TH 8
#define TW 32
#define PR (TH + 2)   // 10 patch rows
#define PC (TW + 2)   // 34 patch cols
#define CIP 68        // padded ci stride (136 B cells: 8B-aligned, even-bank spread)

__device__ __forceinline__ unsigned short f2bf(float f) {
  unsigned u = __builtin_bit_cast(unsigned, f);
  u += 0x7FFFu + ((u >> 16) & 1u);   // RNE
  return (unsigned short)(u >> 16);
}

__global__ __launch_bounds__(64) void ternarize_kernel(const float* __restrict__ w,
                                                       short* __restrict__ T,
                                                       float* __restrict__ alpha) {
  const int co = blockIdx.x, t = threadIdx.x;  // one wave per C_out
  float v[9];
  const float* wp = w + ((size_t)co * 64 + t) * 9;
  float s = 0.f;
#pragma unroll
  for (int j = 0; j < 9; ++j) { v[j] = wp[j]; s += fabsf(v[j]); }
#pragma unroll
  for (int off = 32; off >= 1; off >>= 1) s += __shfl_xor(s, off);
  const float delta = (0.7f / 576.f) * s;
  float cnt = 0.f, asum = 0.f;
#pragma unroll
  for (int j = 0; j < 9; ++j) {
    float a = fabsf(v[j]);
    if (a > delta) { cnt += 1.f; asum += a; }
  }
#pragma unroll
  for (int off = 32; off >= 1; off >>= 1) {
    cnt += __shfl_xor(cnt, off);
    asum += __shfl_xor(asum, off);
  }
  if (cnt == 0.f) cnt = 1.f;
  const float al = fmaxf(asum / cnt, 1e-4f);
#pragma unroll
  for (int j = 0; j < 9; ++j) {
    short tv = v[j] > delta ? (short)0x3F80 : (v[j] < -delta ? (short)0xBF80 : (short)0);
    T[((size_t)j * 64 + co) * 64 + t] = tv;   // [khkw][co][ci] bf16
  }
  if (t == 0) alpha[co] = al;
}

__global__ __launch_bounds__(512, 4) void conv_kernel(const float* __restrict__ x,
                                                      const short* __restrict__ Tw,
                                                      const float* __restrict__ alpha,
                                                      const float* __restrict__ bias,
                                                      float* __restrict__ out) {
  __shared__ short patch[PR][PC][CIP];   // 46240 B, bf16, ci innermost
  const int tid = threadIdx.x;
  const int lane = tid & 63, wid = tid >> 6;
  const int w0 = blockIdx.x * TW;
  const int h0 = blockIdx.y * TH;
  const int n = blockIdx.z;

  // ---- stage x (fp32 global) -> LDS bf16, transposed to [r][c][ci] ----
  for (int i = tid; i < CIN * PR * PC; i += 512) {
    int ci = i / (PR * PC);
    int rc = i - ci * (PR * PC);
    int r = rc / PC;
    int c = rc - r * PC;
    int h = h0 - 1 + r, w = w0 - 1 + c;
    float v = 0.f;
    if ((unsigned)h < (unsigned)HH && (unsigned)w < (unsigned)WW)
      v = x[(((size_t)n * CIN + ci) * HH + h) * WW + w];
    patch[r][c][ci] = (short)f2bf(v);
  }
  __syncthreads();

  f32x4 acc[4][2];
  const f32x4 fz = {0.f, 0.f, 0.f, 0.f};
#pragma unroll
  for (int mi = 0; mi < 4; ++mi)
#pragma unroll
    for (int ni = 0; ni < 2; ++ni) acc[mi][ni] = fz;

  const int l15 = lane & 15, lp = lane >> 4;

#pragma unroll
  for (int kh = 0; kh < 3; ++kh) {
#pragma unroll
    for (int kw = 0; kw < 3; ++kw) {
      const int khkw = kh * 3 + kw;
#pragma unroll
      for (int half = 0; half < 2; ++half) {
        // A frags: T[khkw][16*mi + l15][half*32 + 8*lp + e]  (L2-resident)
        short8 a[4];
        const short* ab = Tw + ((size_t)khkw * 64 + l15) * 64 + half * 32 + lp * 8;
#pragma unroll
        for (int mi = 0; mi < 4; ++mi) a[mi] = *(const short8*)(ab + mi * 16 * 64);
        // B frags: patch[wid+kh][16*ni + l15 + kw][half*32 + 8*lp + e]
        const int r = wid + kh;
        short8 b[2];
#pragma unroll
        for (int ni = 0; ni < 2; ++ni) {
          const int c = ni * 16 + l15 + kw;
          const short* pb = &patch[r][c][half * 32 + lp * 8];
          short4v lo = *(const short4v*)pb;
          short4v hi = *(const short4v*)(pb + 4);
          short8 bv;
          bv[0] = lo[0]; bv[1] = lo[1]; bv[2] = lo[2]; bv[3] = lo[3];
          bv[4] = hi[0]; bv[5] = hi[1]; bv[6] = hi[2]; bv[7] = hi[3];
          b[ni] = bv;
        }
#pragma unroll
        for (int mi = 0; mi < 4; ++mi)
#pragma unroll
          for (int ni = 0; ni < 2; ++ni)
            acc[mi][ni] = __builtin_amdgcn_mfma_f32_16x16x32_bf16(
                __builtin_bit_cast(bf16x8, a[mi]), __builtin_bit_cast(bf16x8, b[ni]),
                acc[mi][ni], 0, 0, 0);
      }
    }
  }

  // ---- epilogue: out = alpha[co]*acc + bias[co] ----
  const int h = h0 + wid;
#pragma unroll
  for (int mi = 0; mi < 4; ++mi) {
#pragma unroll
    for (int r4 = 0; r4 < 4; ++r4) {
      const int co = mi * 16 + lp * 4 + r4;   // D: row=(lane>>4)*4+reg, col=lane&15
      const float sc = alpha[co], bb = bias[co];
#pragma unroll
      for (int ni = 0; ni < 2; ++ni) {
        const int w = w0 + ni * 16 + l15;
        out[(((size_t)n * COUT + co) * HH + h) * WW + w] = acc[mi][ni][r4] * sc + bb;
      }
    }
  }
}

extern "C" void kernel_launch(void* const* d_in, const int* in_sizes, int n_in,
                              void* d_out, int out_size, void* d_ws, size_t ws_size,
                              hipStream_t stream) {
  const float* x = (const float*)d_in[0];
  const float* w = (const float*)d_in[1];
  const float* bias = (const float*)d_in[2];
  float* out = (float*)d_out;

  short* T = (short*)d_ws;                                   // 9*64*64 bf16 = 73728 B
  float* alpha = (float*)((char*)d_ws + 9 * 64 * 64 * 2);    // 64 f32

  ternarize_kernel<<<64, 64, 0, stream>>>(w, T, alpha);
  conv_kernel<<<dim3(WW / TW, HH / TH, 16), 512, 0, stream>>>(x, T, alpha, bias, out);
}

// Round 2
// 425.127 us; speedup vs baseline: 1.5538x; 1.5538x over previous
//
#include <hip/hip_runtime.h>
#include <hip/hip_bf16.h>

// TernaryConv2d: x[16,64,224,224] f32, w[64,64,3,3] f32 -> ternarize (per-co
// {-1,0,+1}*alpha) -> conv3x3 pad1 + bias -> out[16,64,224,224] f32.
//
// R2: (1) ternary weights pre-packed in MFMA fragment order -> conv reads A as
// coalesced 1KB global_load_dwordx4 from L2-hot 72KB buffer; (2) staging is
// one-thread-per-(r,c)-cell: coalesced f32 loads down ci, short8 pack,
// ds_write_b64 (ci innermost); (3) XCD-chunked block swizzle; (4) 3 blocks/CU.

typedef short short8 __attribute__((ext_vector_type(8)));
typedef short short4v __attribute__((ext_vector_type(4)));
typedef float f32x4 __attribute__((ext_vector_type(4)));
typedef __bf16 bf16x8 __attribute__((ext_vector_type(8)));

#define HH 224
#define WW 224
#define CIN 64
#define COUT 64
#define TH 8
#define TW 32
#define PR (TH + 2)   // 10
#define PC (TW + 2)   // 34
#define CIP 68        // ci stride: 136B cells -> 8B aligned, even-bank spread (4-way worst)
#define GX (WW / TW)  // 7
#define GY (HH / TH)  // 28
#define NB (GX * GY * 16)  // 3136 blocks
#define NPX (NB / 8)       // 392 per XCD

__device__ __forceinline__ unsigned short f2bf(float f) {
  unsigned u = __builtin_bit_cast(unsigned, f);
  u += 0x7FFFu + ((u >> 16) & 1u);   // RNE
  return (unsigned short)(u >> 16);
}

// One wave per C_out. Writes T in MFMA-fragment order:
// chunk(j,half,mi) = (j*2+half)*4 + mi   (72 chunks x 1KB)
// lane l = lp*16+l15 holds A[row=mi*16+l15][k=half*32+lp*8+e], e=0..7.
__global__ __launch_bounds__(64) void ternarize_kernel(const float* __restrict__ w,
                                                       short* __restrict__ Tf,
                                                       float* __restrict__ alpha) {
  const int co = blockIdx.x, t = threadIdx.x;  // t = ci
  float v[9];
  const float* wp = w + ((size_t)co * 64 + t) * 9;
  float s = 0.f;
#pragma unroll
  for (int j = 0; j < 9; ++j) { v[j] = wp[j]; s += fabsf(v[j]); }
#pragma unroll
  for (int off = 32; off >= 1; off >>= 1) s += __shfl_xor(s, off);
  const float delta = (0.7f / 576.f) * s;
  float cnt = 0.f, asum = 0.f;
#pragma unroll
  for (int j = 0; j < 9; ++j) {
    float a = fabsf(v[j]);
    if (a > delta) { cnt += 1.f; asum += a; }
  }
#pragma unroll
  for (int off = 32; off >= 1; off >>= 1) {
    cnt += __shfl_xor(cnt, off);
    asum += __shfl_xor(asum, off);
  }
  if (cnt == 0.f) cnt = 1.f;
  const float al = fmaxf(asum / cnt, 1e-4f);
  const int mi = co >> 4, l15 = co & 15;
  const int half = t >> 5, lp = (t >> 3) & 3, e = t & 7;
  const int lane = lp * 16 + l15;
#pragma unroll
  for (int j = 0; j < 9; ++j) {
    short tv = v[j] > delta ? (short)0x3F80 : (v[j] < -delta ? (short)0xBF80 : (short)0);
    const int chunk = (j * 2 + half) * 4 + mi;
    Tf[(size_t)chunk * 512 + lane * 8 + e] = tv;
  }
  if (t == 0) alpha[co] = al;
}

__global__ __launch_bounds__(512, 6) void conv_kernel(const float* __restrict__ x,
                                                      const short* __restrict__ Tw,
                                                      const float* __restrict__ alpha,
                                                      const float* __restrict__ bias,
                                                      float* __restrict__ out) {
  __shared__ short patch[PR * PC][CIP];   // 46240 B
  const int tid = threadIdx.x;
  const int lane = tid & 63, wid = tid >> 6;
  // XCD-chunked swizzle: XCD x gets contiguous sid range -> halo neighbors share L2
  int sid = (int)blockIdx.x;
  sid = (sid & 7) * NPX + (sid >> 3);
  const int bx = sid % GX;
  const int t2 = sid / GX;
  const int by = t2 % GY;
  const int n = t2 / GY;
  const int w0 = bx * TW, h0 = by * TH;

  // ---- stage: thread = one (r,c) cell; coalesced f32 loads down ci ----
  if (tid < PR * PC) {
    const int r = tid / PC, c = tid - r * PC;
    const int h = h0 - 1 + r, w = w0 - 1 + c;
    const bool inb = ((unsigned)h < (unsigned)HH) & ((unsigned)w < (unsigned)WW);
    const float* xp = x + ((long long)n * CIN * HH + (long long)h) * WW + w;
#pragma unroll
    for (int g = 0; g < 8; ++g) {
      short8 pk;
#pragma unroll
      for (int e = 0; e < 8; ++e) {
        float v = inb ? xp[(long long)(g * 8 + e) * HH * WW] : 0.f;
        pk[e] = (short)f2bf(v);
      }
      short4v lo = {pk[0], pk[1], pk[2], pk[3]};
      short4v hi = {pk[4], pk[5], pk[6], pk[7]};
      *(short4v*)&patch[tid][g * 8] = lo;
      *(short4v*)&patch[tid][g * 8 + 4] = hi;
    }
  }
  __syncthreads();

  f32x4 acc[4][2];
  const f32x4 fz = {0.f, 0.f, 0.f, 0.f};
#pragma unroll
  for (int mi = 0; mi < 4; ++mi)
#pragma unroll
    for (int ni = 0; ni < 2; ++ni) acc[mi][ni] = fz;

  const int l15 = lane & 15, lp = lane >> 4;
  const short* tf = Tw + lane * 8;   // + chunk*512 per fragment

#pragma unroll
  for (int kh = 0; kh < 3; ++kh) {
#pragma unroll
    for (int kw = 0; kw < 3; ++kw) {
      const int j = kh * 3 + kw;
      const int rr = wid + kh;
#pragma unroll
      for (int half = 0; half < 2; ++half) {
        // A: coalesced 1KB chunk, L2-hot, exec-independent -> pipelinable
        short8 a[4];
#pragma unroll
        for (int mi = 0; mi < 4; ++mi)
          a[mi] = *(const short8*)(tf + (((j * 2 + half) * 4 + mi) << 9));
        // B: patch[rr][ni*16 + l15 + kw][half*32 + lp*8 ..+7]
        short8 b[2];
#pragma unroll
        for (int ni = 0; ni < 2; ++ni) {
          const short* pb = &patch[rr * PC + ni * 16 + l15 + kw][half * 32 + lp * 8];
          short4v lo = *(const short4v*)pb;
          short4v hi = *(const short4v*)(pb + 4);
          short8 bv;
          bv[0] = lo[0]; bv[1] = lo[1]; bv[2] = lo[2]; bv[3] = lo[3];
          bv[4] = hi[0]; bv[5] = hi[1]; bv[6] = hi[2]; bv[7] = hi[3];
          b[ni] = bv;
        }
#pragma unroll
        for (int mi = 0; mi < 4; ++mi)
#pragma unroll
          for (int ni = 0; ni < 2; ++ni)
            acc[mi][ni] = __builtin_amdgcn_mfma_f32_16x16x32_bf16(
                __builtin_bit_cast(bf16x8, a[mi]), __builtin_bit_cast(bf16x8, b[ni]),
                acc[mi][ni], 0, 0, 0);
      }
    }
  }

  // ---- epilogue: out = alpha[co]*acc + bias[co] ----
  const int h = h0 + wid;
#pragma unroll
  for (int mi = 0; mi < 4; ++mi) {
#pragma unroll
    for (int r4 = 0; r4 < 4; ++r4) {
      const int co = mi * 16 + lp * 4 + r4;   // D: row=(lane>>4)*4+reg, col=lane&15
      const float sc = alpha[co], bb = bias[co];
#pragma unroll
      for (int ni = 0; ni < 2; ++ni) {
        const int w = w0 + ni * 16 + l15;
        out[(((long long)n * COUT + co) * HH + h) * WW + w] = acc[mi][ni][r4] * sc + bb;
      }
    }
  }
}

extern "C" void kernel_launch(void* const* d_in, const int* in_sizes, int n_in,
                              void* d_out, int out_size, void* d_ws, size_t ws_size,
                              hipStream_t stream) {
  const float* x = (const float*)d_in[0];
  const float* w = (const float*)d_in[1];
  const float* bias = (const float*)d_in[2];
  float* out = (float*)d_out;

  short* Tf = (short*)d_ws;                                  // 72 KiB fragment-packed
  float* alpha = (float*)((char*)d_ws + 9 * 64 * 64 * 2);    // 64 f32

  ternarize_kernel<<<64, 64, 0, stream>>>(w, Tf, alpha);
  conv_kernel<<<NB, 512, 0, stream>>>(x, Tf, alpha, bias, out);
}